// Round 3
// baseline (121.975 us; speedup 1.0000x reference)
//
#include <hip/hip_runtime.h>

#define NS 1024
#define KD 256
#define H  256
#define NBLK 256   // pair grid = 8 x 32

// ---------------------------------------------------------------------------
// proj_kernel: PX = X @ W1[:KD], PYB = Y @ W1[KD:] + b1
// grid (H/64=4, NS/32=32, 2), block 256. z=0 -> PX, z=1 -> PYB.
// x staged once in LDS (transposed); W read from global (L2-resident,
// coalesced 256B/wave, software-pipelined by unroll-8).
// ---------------------------------------------------------------------------
__global__ __launch_bounds__(256) void proj_kernel(
    const float* __restrict__ X, const float* __restrict__ Y,
    const float* __restrict__ W1, const float* __restrict__ b1,
    float* __restrict__ PX, float* __restrict__ PYB, int* __restrict__ counter)
{
    if (blockIdx.x == 0 && blockIdx.y == 0 && blockIdx.z == 0 && threadIdx.x == 0)
        *counter = 0;   // proj runs before pair (stream order) -> init for last-block

    const int z = blockIdx.z;
    const float* __restrict__ A = z ? Y : X;
    const float* __restrict__ W = W1 + (z ? KD * H : 0);
    float* __restrict__ OUT = z ? PYB : PX;

    __shared__ float xs[KD][34];   // transposed [k][i-local]; pad 34 keeps b64 align, 2-way banks

    const int tid = threadIdx.x;
    const int tx = tid & 15;       // h quad (4 cols)
    const int ty = tid >> 4;       // 0..15 (2 rows)
    const int i0 = blockIdx.y * 32, h0 = blockIdx.x * 64;

    // stage x rows transposed, ONCE (32 rows x 256 k)
    {
        const int ii = tid & 31, q = tid >> 5;  // q 0..7
        #pragma unroll
        for (int u = 0; u < 8; ++u) {
            const int k = u * 32 + q * 4;
            float4 v = *(const float4*)&A[(i0 + ii) * KD + k];
            xs[k + 0][ii] = v.x; xs[k + 1][ii] = v.y;
            xs[k + 2][ii] = v.z; xs[k + 3][ii] = v.w;
        }
    }
    __syncthreads();

    float acc[2][4] = {};
    const float* __restrict__ wp = &W[h0 + tx * 4];

    #pragma unroll 8
    for (int k = 0; k < KD; ++k) {
        float4 w4 = *(const float4*)&wp[k * H];
        const float x0 = xs[k][ty * 2 + 0];
        const float x1 = xs[k][ty * 2 + 1];
        acc[0][0] = fmaf(x0, w4.x, acc[0][0]);
        acc[0][1] = fmaf(x0, w4.y, acc[0][1]);
        acc[0][2] = fmaf(x0, w4.z, acc[0][2]);
        acc[0][3] = fmaf(x0, w4.w, acc[0][3]);
        acc[1][0] = fmaf(x1, w4.x, acc[1][0]);
        acc[1][1] = fmaf(x1, w4.y, acc[1][1]);
        acc[1][2] = fmaf(x1, w4.z, acc[1][2]);
        acc[1][3] = fmaf(x1, w4.w, acc[1][3]);
    }

    float bv[4] = {0.f, 0.f, 0.f, 0.f};
    if (z) *(float4*)bv = *(const float4*)&b1[h0 + tx * 4];
    #pragma unroll
    for (int r = 0; r < 2; ++r) {
        float o[4];
        #pragma unroll
        for (int c = 0; c < 4; ++c) o[c] = acc[r][c] + bv[c];
        *(float4*)&OUT[(i0 + ty * 2 + r) * H + h0 + tx * 4] = *(float4*)o;
    }
}

// ---------------------------------------------------------------------------
// pair_kernel: 32(i) x 128(j) tiles, R2C8 per thread (cols split tx*4 / 64+tx*4),
// h tiled by 64 with double-buffered transposed LDS. Epilogue: exp-sum + diag,
// block reduce, last-block final reduction -> out.
// grid (8, 32) = 256 blocks, 256 threads.
// ---------------------------------------------------------------------------
#define PXPAD 132
#define PYPAD 34

__global__ __launch_bounds__(256) void pair_kernel(
    const float* __restrict__ PX, const float* __restrict__ PYB,
    const float* __restrict__ W2, const float* __restrict__ b2,
    float* __restrict__ eparts, float* __restrict__ dparts,
    int* __restrict__ counter, float* __restrict__ out)
{
    __shared__ float pxt[2][64][PXPAD];   // [buf][h][j]  67.6 KB
    __shared__ float pyt[2][64][PYPAD];   // [buf][h][i]  17.4 KB
    __shared__ float red_e[256], red_d[256];
    __shared__ double sde[256], sdd[256];
    __shared__ int lastflag;

    const int tid = threadIdx.x;
    const int tx = tid & 15;       // 0..15
    const int ty = tid >> 4;       // 0..15 (2 rows)
    const int j0 = blockIdx.x * 128, i0 = blockIdx.y * 32;

    // staging thread mappings
    const int su = tid & 7;        // px: 8 lanes cover 128B contiguous h
    const int sjb = tid >> 3;      // 0..31
    const int sii = tid & 31;      // py: row
    const int sq = tid >> 5;       // 0..7

    float acc[2][8] = {};

#define STAGE(T, B)                                                                  \
    {                                                                                \
        const int hb = (T) * 64;                                                     \
        _Pragma("unroll")                                                            \
        for (int t = 0; t < 4; ++t) {                                                \
            _Pragma("unroll")                                                        \
            for (int s = 0; s < 2; ++s) {                                            \
                const int j = sjb + 32 * t;                                          \
                const int hh = (su + 8 * s) * 4;                                     \
                float4 v = *(const float4*)&PX[(j0 + j) * H + hb + hh];              \
                pxt[B][hh + 0][j] = v.x; pxt[B][hh + 1][j] = v.y;                    \
                pxt[B][hh + 2][j] = v.z; pxt[B][hh + 3][j] = v.w;                    \
            }                                                                        \
        }                                                                            \
        _Pragma("unroll")                                                            \
        for (int s = 0; s < 2; ++s) {                                                \
            const int hh = sq * 8 + s * 4;                                           \
            float4 v = *(const float4*)&PYB[(i0 + sii) * H + hb + hh];               \
            pyt[B][hh + 0][sii] = v.x; pyt[B][hh + 1][sii] = v.y;                    \
            pyt[B][hh + 2][sii] = v.z; pyt[B][hh + 3][sii] = v.w;                    \
        }                                                                            \
    }

    STAGE(0, 0);
    __syncthreads();

    for (int t = 0; t < 4; ++t) {
        const int cur = t & 1;
        if (t < 3) {
            if ((t & 1) == 0) STAGE(t + 1, 1)
            else              STAGE(t + 1, 0)
        }
        const int hb = t * 64;
        #pragma unroll 4
        for (int hh = 0; hh < 64; ++hh) {
            const float w = W2[hb + hh];           // uniform -> scalar load
            const float py0 = pyt[cur][hh][ty * 2 + 0];
            const float py1 = pyt[cur][hh][ty * 2 + 1];
            float a4[4], b4[4];
            *(float4*)a4 = *(const float4*)&pxt[cur][hh][tx * 4];
            *(float4*)b4 = *(const float4*)&pxt[cur][hh][64 + tx * 4];
            #pragma unroll
            for (int c = 0; c < 4; ++c) {
                acc[0][c]     = fmaf(fmaxf(py0 + a4[c], 0.f), w, acc[0][c]);
                acc[1][c]     = fmaf(fmaxf(py1 + a4[c], 0.f), w, acc[1][c]);
                acc[0][4 + c] = fmaf(fmaxf(py0 + b4[c], 0.f), w, acc[0][4 + c]);
                acc[1][4 + c] = fmaf(fmaxf(py1 + b4[c], 0.f), w, acc[1][4 + c]);
            }
        }
        __syncthreads();
    }

    // epilogue: t1 = acc + (b2-1); exp-sum + diagonal (t0 = t1[i,i] + 1)
    const float c0 = b2[0] - 1.0f;
    float esum = 0.f, dsum = 0.f;
    #pragma unroll
    for (int r = 0; r < 2; ++r) {
        const int irow = i0 + ty * 2 + r;
        #pragma unroll
        for (int g = 0; g < 2; ++g)
            #pragma unroll
            for (int c = 0; c < 4; ++c) {
                const float t1 = acc[r][g * 4 + c] + c0;
                esum += expf(t1);
                if (irow == j0 + g * 64 + tx * 4 + c) dsum += t1 + 1.0f;
            }
    }

    red_e[tid] = esum;
    red_d[tid] = dsum;
    __syncthreads();
    for (int s = 128; s > 0; s >>= 1) {
        if (tid < s) {
            red_e[tid] += red_e[tid + s];
            red_d[tid] += red_d[tid + s];
        }
        __syncthreads();
    }

    const int bid = blockIdx.y * gridDim.x + blockIdx.x;  // 0..255
    if (tid == 0) {
        __hip_atomic_store(&eparts[bid], red_e[0], __ATOMIC_RELAXED, __HIP_MEMORY_SCOPE_AGENT);
        __hip_atomic_store(&dparts[bid], red_d[0], __ATOMIC_RELAXED, __HIP_MEMORY_SCOPE_AGENT);
        __threadfence();
        const int prev = __hip_atomic_fetch_add(counter, 1, __ATOMIC_ACQ_REL, __HIP_MEMORY_SCOPE_AGENT);
        lastflag = (prev == NBLK - 1);
    }
    __syncthreads();

    if (lastflag) {
        __threadfence();
        sde[tid] = (double)__hip_atomic_load(&eparts[tid], __ATOMIC_RELAXED, __HIP_MEMORY_SCOPE_AGENT);
        sdd[tid] = (double)__hip_atomic_load(&dparts[tid], __ATOMIC_RELAXED, __HIP_MEMORY_SCOPE_AGENT);
        __syncthreads();
        for (int s = 128; s > 0; s >>= 1) {
            if (tid < s) { sde[tid] += sde[tid + s]; sdd[tid] += sdd[tid + s]; }
            __syncthreads();
        }
        if (tid == 0)
            out[0] = (float)(sdd[0] / (double)NS - sde[0] / ((double)NS * (double)NS));
    }
}

// ---------------------------------------------------------------------------
extern "C" void kernel_launch(void* const* d_in, const int* in_sizes, int n_in,
                              void* d_out, int out_size, void* d_ws, size_t ws_size,
                              hipStream_t stream)
{
    const float* X  = (const float*)d_in[0];
    const float* Y  = (const float*)d_in[1];
    const float* W1 = (const float*)d_in[2];
    const float* b1 = (const float*)d_in[3];
    const float* W2 = (const float*)d_in[4];
    const float* b2 = (const float*)d_in[5];
    float* out = (float*)d_out;

    float* PX     = (float*)d_ws;            // [NS][H]
    float* PYB    = PX + NS * H;             // [NS][H]
    float* eparts = PYB + NS * H;            // [256]
    float* dparts = eparts + 256;            // [256]
    int*   counter = (int*)(dparts + 256);

    proj_kernel<<<dim3(H / 64, NS / 32, 2), 256, 0, stream>>>(X, Y, W1, b1, PX, PYB, counter);
    pair_kernel<<<dim3(8, 32), 256, 0, stream>>>(PX, PYB, W2, b2, eparts, dparts, counter, out);
}